// Round 11
// baseline (454.218 us; speedup 1.0000x reference)
//
#include <hip/hip_runtime.h>
#include <cstdint>
#include <cstddef>

#define NEG_SLOPE 0.2f

__device__ __forceinline__ float lrelu(float v) { return v >= 0.f ? v : NEG_SLOPE * v; }

// bf16 pack/unpack (round-to-nearest-even)
__device__ __forceinline__ unsigned short f2bf(float x) {
    union { float f; uint32_t u; } v; v.f = x;
    uint32_t r = v.u + 0x7FFFu + ((v.u >> 16) & 1u);
    return (unsigned short)(r >> 16);
}
__device__ __forceinline__ float bf2f_lo(uint32_t u) {
    union { uint32_t u; float f; } v; v.u = u << 16;
    return v.f;
}
__device__ __forceinline__ float bf2f_hi(uint32_t u) {
    union { uint32_t u; float f; } v; v.u = u & 0xFFFF0000u;
    return v.f;
}

// ==================== CSR build ====================
// pass 1: 8-way-spread degree count; atomic return = slot within (dst, copy k)
__global__ void k_degpos8(const int* __restrict__ A1, const int* __restrict__ A2,
                          const int* __restrict__ A3, int* __restrict__ deg8,
                          int* __restrict__ epos, int E, int N) {
    int e = blockIdx.x * blockDim.x + threadIdx.x;
    if (e >= E) return;
    int r = blockIdx.y;
    int k = blockIdx.x & 7;
    const int* A = (r == 0) ? A1 : (r == 1) ? A2 : A3;
    int dst = A[E + e];
    epos[(size_t)r * E + e] = atomicAdd(&deg8[(size_t)((r << 3) + k) * N + dst], 1);
}

// scan A: fold 8 sub-histograms -> deg + per-copy local offsets (startk, pre-base),
// plus block-local exclusive scan of deg -> start, block sums -> bsum
__global__ void k_scanA2(const int* __restrict__ deg8, int* __restrict__ deg,
                         int* __restrict__ startk, int* __restrict__ start,
                         int* __restrict__ bsum, int total, int N) {
    __shared__ int tmp[256];
    int t = threadIdx.x;
    int base = blockIdx.x * 1024 + t * 4;
    int v[4]; int s = 0;
    #pragma unroll
    for (int m = 0; m < 4; ++m) {
        int g = base + m;
        int sum8 = 0;
        if (g < total) {
            int r = g / N;
            int n = g - r * N;
            #pragma unroll
            for (int k = 0; k < 8; ++k) {
                size_t idx = (size_t)((r << 3) + k) * N + n;
                int dv = deg8[idx];
                startk[idx] = sum8;
                sum8 += dv;
            }
            deg[g] = sum8;
        }
        v[m] = sum8; s += sum8;
    }
    tmp[t] = s; __syncthreads();
    for (int off = 1; off < 256; off <<= 1) {
        int x = (t >= off) ? tmp[t - off] : 0; __syncthreads();
        tmp[t] += x; __syncthreads();
    }
    int run = tmp[t] - s;
    #pragma unroll
    for (int m = 0; m < 4; ++m) {
        if (base + m < total) start[base + m] = run;
        run += v[m];
    }
    if (t == 255) bsum[blockIdx.x] = tmp[255];
}

// scan B: one block, exclusive scan of block sums
__global__ void k_scanB(int* __restrict__ bsum, int nb) {
    __shared__ int tmp[256];
    int t = threadIdx.x;
    int v[4]; int s = 0;
    #pragma unroll
    for (int k = 0; k < 4; ++k) { int i = t * 4 + k; v[k] = (i < nb) ? bsum[i] : 0; s += v[k]; }
    tmp[t] = s; __syncthreads();
    for (int off = 1; off < 256; off <<= 1) {
        int x = (t >= off) ? tmp[t - off] : 0; __syncthreads();
        tmp[t] += x; __syncthreads();
    }
    int run = tmp[t] - s;
    #pragma unroll
    for (int k = 0; k < 4; ++k) {
        int i = t * 4 + k;
        if (i < nb) { int vv = v[k]; bsum[i] = run; run += vv; }
    }
}

// scan C: finalize global base; push base into the 8 startk copies
__global__ void k_scanC2(int* __restrict__ start, const int* __restrict__ bsum,
                         int* __restrict__ startk, int total, int N, int E) {
    int g = blockIdx.x * blockDim.x + threadIdx.x;
    if (g >= total) return;
    int r = g / N;
    int n = g - r * N;
    int base = start[g] + bsum[g >> 10] - r * E;
    start[g] = base;
    #pragma unroll
    for (int k = 0; k < 8; ++k)
        startk[(size_t)((r << 3) + k) * N + n] += base;
}

// pass 2: no atomics — pos = startk[k][dst] + epos
__global__ void k_scatter2(const int* __restrict__ A1, const int* __restrict__ A2,
                           const int* __restrict__ A3,
                           const int* __restrict__ startk, const int* __restrict__ epos,
                           int* __restrict__ csr, int E, int N) {
    int e = blockIdx.x * blockDim.x + threadIdx.x;
    if (e >= E) return;
    int r = blockIdx.y;
    int k = blockIdx.x & 7;
    const int* A = (r == 0) ? A1 : (r == 1) ? A2 : A3;
    int src = A[e], dst = A[E + e];
    int pos = startk[(size_t)((r << 3) + k) * N + dst] + epos[(size_t)r * E + e];
    csr[(size_t)r * E + pos] = src;
}

// ==================== layer 1: register-W linear + scores ====================
#define L1_NODES 64
__global__ __launch_bounds__(384) void k_linear1(
        const float* __restrict__ X,
        const float* __restrict__ W1, const float* __restrict__ W2,
        const float* __restrict__ W3,
        const float* __restrict__ as1, const float* __restrict__ ad1,
        const float* __restrict__ as2, const float* __restrict__ ad2,
        const float* __restrict__ as3, const float* __restrict__ ad3,
        unsigned short* __restrict__ h_bf,
        float* __restrict__ s_src, float* __restrict__ s_dst, int N) {
    __shared__ float Xs[L1_NODES][64];
    int t = threadIdx.x;
    int n0 = blockIdx.x * L1_NODES;
    {
        const float4* X4 = reinterpret_cast<const float4*>(X);
        float4* Xs4 = reinterpret_cast<float4*>(&Xs[0][0]);
        for (int i = t; i < L1_NODES * 16; i += 384) {
            int nl = i >> 4;
            float4 xv = make_float4(0.f, 0.f, 0.f, 0.f);
            if (n0 + nl < N) xv = X4[(size_t)(n0 + nl) * 16 + (i & 15)];
            Xs4[i] = xv;
        }
    }
    int r = t >> 7, col = t & 127, head = (t >> 4) & 7, c = t & 15;
    const float* Wp = ((r == 0) ? W1 : (r == 1) ? W2 : W3) + col;
    float Wc[64];
    #pragma unroll
    for (int k = 0; k < 64; ++k) Wc[k] = Wp[(size_t)k * 128];
    float as_v = ((r == 0) ? as1 : (r == 1) ? as2 : as3)[head * 16 + c];
    float ad_v = ((r == 0) ? ad1 : (r == 1) ? ad2 : ad3)[head * 16 + c];
    __syncthreads();
    int nmax = min(L1_NODES, N - n0);
    int rh = (r << 3) + head;
    for (int n = 0; n < nmax; ++n) {
        const float4* xr = reinterpret_cast<const float4*>(&Xs[n][0]);
        float a0 = 0.f, a1 = 0.f, a2 = 0.f, a3 = 0.f;
        #pragma unroll
        for (int k4 = 0; k4 < 16; ++k4) {
            float4 xv = xr[k4];
            a0 = fmaf(xv.x, Wc[k4 * 4 + 0], a0);
            a1 = fmaf(xv.y, Wc[k4 * 4 + 1], a1);
            a2 = fmaf(xv.z, Wc[k4 * 4 + 2], a2);
            a3 = fmaf(xv.w, Wc[k4 * 4 + 3], a3);
        }
        float acc = (a0 + a1) + (a2 + a3);
        h_bf[(size_t)(n0 + n) * 384 + t] = f2bf(acc);
        float ss = acc * as_v, sd = acc * ad_v;
        ss += __shfl_xor(ss, 1); ss += __shfl_xor(ss, 2);
        ss += __shfl_xor(ss, 4); ss += __shfl_xor(ss, 8);
        sd += __shfl_xor(sd, 1); sd += __shfl_xor(sd, 2);
        sd += __shfl_xor(sd, 4); sd += __shfl_xor(sd, 8);
        if (c == 0) {
            s_src[(size_t)(n0 + n) * 24 + rh] = ss;
            s_dst[(size_t)(n0 + n) * 24 + rh] = sd;
        }
    }
}

// ==================== layer-1 aggregation (8-deep gather pipeline) ====================
__global__ __launch_bounds__(64) void k_agg1(
        const unsigned short* __restrict__ h_bf,
        const float* __restrict__ s_src, const float* __restrict__ s_dst,
        const int* __restrict__ deg, const int* __restrict__ start,
        const int* __restrict__ csr,
        const float* __restrict__ b1, const float* __restrict__ b2,
        const float* __restrict__ b3,
        unsigned short* __restrict__ Xc, int E, int N) {
    __shared__ int sidx[64];
    __shared__ float sex[64 * 8];
    int n = blockIdx.x;
    int r = blockIdx.y;
    int j = threadIdx.x;              // uint channel-pair index 0..63
    int h = j >> 3;                   // head (16 ch = 8 uints per head)
    int rh = r * 8 + h;
    int s0 = start[(size_t)r * N + n];
    int d  = deg[(size_t)r * N + n];
    const uint32_t* hb = reinterpret_cast<const uint32_t*>(h_bf);
    int off = r * 64 + j;
    float sd = s_dst[(size_t)n * 24 + rh];
    float ex0 = __expf(lrelu(s_src[(size_t)n * 24 + rh] + sd));
    float denom = ex0;
    uint32_t hv0 = hb[(size_t)n * 192 + off];
    float accx = ex0 * bf2f_lo(hv0);
    float accy = ex0 * bf2f_hi(hv0);
    int hA = j & 7;
    float sdA = s_dst[(size_t)n * 24 + r * 8 + hA];
    const int* cs = csr + (size_t)r * E + s0;
    for (int c0 = 0; c0 < d; c0 += 64) {
        int dc = min(64, d - c0);
        if (j < dc) sidx[j] = cs[c0 + j];
        __syncthreads();
        // phase A: one exp per (neighbor, head); 2 loads issued before use
        for (int p = j; p < dc * 8; p += 128) {
            int p1 = p + 64;
            float v0 = s_src[(size_t)sidx[p >> 3] * 24 + r * 8 + hA];
            float v1 = (p1 < dc * 8) ? s_src[(size_t)sidx[p1 >> 3] * 24 + r * 8 + hA] : 0.f;
            sex[p] = __expf(lrelu(v0 + sdA));
            if (p1 < dc * 8) sex[p1] = __expf(lrelu(v1 + sdA));
        }
        __syncthreads();
        // phase B: 8 independent gathers in flight before any FMA
        int i = 0;
        for (; i + 8 <= dc; i += 8) {
            uint32_t v0 = hb[(size_t)sidx[i + 0] * 192 + off];
            uint32_t v1 = hb[(size_t)sidx[i + 1] * 192 + off];
            uint32_t v2 = hb[(size_t)sidx[i + 2] * 192 + off];
            uint32_t v3 = hb[(size_t)sidx[i + 3] * 192 + off];
            uint32_t v4 = hb[(size_t)sidx[i + 4] * 192 + off];
            uint32_t v5 = hb[(size_t)sidx[i + 5] * 192 + off];
            uint32_t v6 = hb[(size_t)sidx[i + 6] * 192 + off];
            uint32_t v7 = hb[(size_t)sidx[i + 7] * 192 + off];
            float e0 = sex[(i + 0) * 8 + h], e1 = sex[(i + 1) * 8 + h];
            float e2 = sex[(i + 2) * 8 + h], e3 = sex[(i + 3) * 8 + h];
            float e4 = sex[(i + 4) * 8 + h], e5 = sex[(i + 5) * 8 + h];
            float e6 = sex[(i + 6) * 8 + h], e7 = sex[(i + 7) * 8 + h];
            denom += ((e0 + e1) + (e2 + e3)) + ((e4 + e5) + (e6 + e7));
            accx = fmaf(e0, bf2f_lo(v0), accx); accy = fmaf(e0, bf2f_hi(v0), accy);
            accx = fmaf(e1, bf2f_lo(v1), accx); accy = fmaf(e1, bf2f_hi(v1), accy);
            accx = fmaf(e2, bf2f_lo(v2), accx); accy = fmaf(e2, bf2f_hi(v2), accy);
            accx = fmaf(e3, bf2f_lo(v3), accx); accy = fmaf(e3, bf2f_hi(v3), accy);
            accx = fmaf(e4, bf2f_lo(v4), accx); accy = fmaf(e4, bf2f_hi(v4), accy);
            accx = fmaf(e5, bf2f_lo(v5), accx); accy = fmaf(e5, bf2f_hi(v5), accy);
            accx = fmaf(e6, bf2f_lo(v6), accx); accy = fmaf(e6, bf2f_hi(v6), accy);
            accx = fmaf(e7, bf2f_lo(v7), accx); accy = fmaf(e7, bf2f_hi(v7), accy);
        }
        if (i + 4 <= dc) {
            uint32_t v0 = hb[(size_t)sidx[i + 0] * 192 + off];
            uint32_t v1 = hb[(size_t)sidx[i + 1] * 192 + off];
            uint32_t v2 = hb[(size_t)sidx[i + 2] * 192 + off];
            uint32_t v3 = hb[(size_t)sidx[i + 3] * 192 + off];
            float e0 = sex[(i + 0) * 8 + h], e1 = sex[(i + 1) * 8 + h];
            float e2 = sex[(i + 2) * 8 + h], e3 = sex[(i + 3) * 8 + h];
            denom += (e0 + e1) + (e2 + e3);
            accx = fmaf(e0, bf2f_lo(v0), accx); accy = fmaf(e0, bf2f_hi(v0), accy);
            accx = fmaf(e1, bf2f_lo(v1), accx); accy = fmaf(e1, bf2f_hi(v1), accy);
            accx = fmaf(e2, bf2f_lo(v2), accx); accy = fmaf(e2, bf2f_hi(v2), accy);
            accx = fmaf(e3, bf2f_lo(v3), accx); accy = fmaf(e3, bf2f_hi(v3), accy);
            i += 4;
        }
        for (; i < dc; ++i) {
            float ex = sex[i * 8 + h];
            uint32_t hv = hb[(size_t)sidx[i] * 192 + off];
            denom += ex;
            accx = fmaf(ex, bf2f_lo(hv), accx);
            accy = fmaf(ex, bf2f_hi(hv), accy);
        }
        __syncthreads();
    }
    const float* b = (r == 0) ? b1 : (r == 1) ? b2 : b3;
    float inv = 1.0f / (denom + 1e-16f);
    float ox = accx * inv + b[2 * j];
    float oy = accy * inv + b[2 * j + 1];
    ox = (ox > 0.f) ? ox : 0.f;
    oy = (oy > 0.f) ? oy : 0.f;
    uint32_t packed = (uint32_t)f2bf(ox) | ((uint32_t)f2bf(oy) << 16);
    reinterpret_cast<uint32_t*>(Xc)[(size_t)n * 192 + off] = packed;
}

// ==================== layer 2: linear ====================
__global__ void k_linear2(const unsigned short* __restrict__ Xc,
                          const float* __restrict__ W1, const float* __restrict__ W2,
                          const float* __restrict__ W3,
                          float* __restrict__ h2, int N) {
    int gid = blockIdx.x * 1024 + threadIdx.x;
    int node = gid >> 6;
    int lane = gid & 63;
    if (node >= N) return;
    const uint32_t* xp = reinterpret_cast<const uint32_t*>(Xc) + (size_t)node * 192;
    const float2* W1v = reinterpret_cast<const float2*>(W1);
    const float2* W2v = reinterpret_cast<const float2*>(W2);
    const float2* W3v = reinterpret_cast<const float2*>(W3);
    float s0 = 0.f, s1 = 0.f, s2 = 0.f;
    #pragma unroll
    for (int j0 = 0; j0 < 192; j0 += 64) {
        uint32_t xv = xp[j0 + lane];
        float x0 = bf2f_lo(xv), x1 = bf2f_hi(xv);
        float2 w1 = W1v[j0 + lane], w2 = W2v[j0 + lane], w3 = W3v[j0 + lane];
        s0 = fmaf(x0, w1.x, s0); s0 = fmaf(x1, w1.y, s0);
        s1 = fmaf(x0, w2.x, s1); s1 = fmaf(x1, w2.y, s1);
        s2 = fmaf(x0, w3.x, s2); s2 = fmaf(x1, w3.y, s2);
    }
    #pragma unroll
    for (int off = 32; off > 0; off >>= 1) {
        s0 += __shfl_down(s0, off);
        s1 += __shfl_down(s1, off);
        s2 += __shfl_down(s2, off);
    }
    if (lane == 0) {
        h2[(size_t)node * 3 + 0] = s0;
        h2[(size_t)node * 3 + 1] = s1;
        h2[(size_t)node * 3 + 2] = s2;
    }
}

// ==================== layer-2 aggregation + final projection ====================
// 8 lanes per (node, branch); blockDim 384 = 48 units = 16 nodes; 2-deep gather
__global__ __launch_bounds__(384) void k_agg2f(
        const float* __restrict__ h2,
        const int* __restrict__ deg, const int* __restrict__ start,
        const int* __restrict__ csr,
        const float* __restrict__ as1, const float* __restrict__ ad1,
        const float* __restrict__ as2, const float* __restrict__ ad2,
        const float* __restrict__ as3, const float* __restrict__ ad3,
        const float* __restrict__ b1, const float* __restrict__ b2,
        const float* __restrict__ b3,
        const float* __restrict__ ln_w, const float* __restrict__ ln_b,
        float* __restrict__ out, int E, int N) {
    __shared__ float ys[48];
    int tl = threadIdx.x;
    int pl = tl >> 3;                 // unit 0..47
    int q  = tl & 7;                  // lane in unit
    int id = blockIdx.x * 48 + pl;
    bool valid = id < 3 * N;
    int n = id / 3;
    int r = id - 3 * n;
    float denom = 0.f, acc = 0.f;
    if (valid) {
        float a_s = ((r == 0) ? as1 : (r == 1) ? as2 : as3)[0];
        float a_d = ((r == 0) ? ad1 : (r == 1) ? ad2 : ad3)[0];
        int s0 = start[(size_t)r * N + n];
        int d  = deg[(size_t)r * N + n];
        float hd = h2[id];
        float sd = a_d * hd;
        const int* cs = csr + (size_t)r * E + s0;
        int i = q;
        for (; i + 8 < d; i += 16) {
            float hva = h2[(size_t)cs[i] * 3 + r];
            float hvb = h2[(size_t)cs[i + 8] * 3 + r];
            float eA = __expf(lrelu(fmaf(a_s, hva, sd)));
            float eB = __expf(lrelu(fmaf(a_s, hvb, sd)));
            denom += eA + eB;
            acc = fmaf(eA, hva, acc);
            acc = fmaf(eB, hvb, acc);
        }
        if (i < d) {
            float hva = h2[(size_t)cs[i] * 3 + r];
            float eA = __expf(lrelu(fmaf(a_s, hva, sd)));
            denom += eA;
            acc = fmaf(eA, hva, acc);
        }
        if (q == 0) {
            float ev = __expf(lrelu(fmaf(a_s, hd, sd)));
            denom += ev;
            acc = fmaf(ev, hd, acc);
        }
    }
    denom += __shfl_xor(denom, 1); denom += __shfl_xor(denom, 2); denom += __shfl_xor(denom, 4);
    acc   += __shfl_xor(acc, 1);   acc   += __shfl_xor(acc, 2);   acc   += __shfl_xor(acc, 4);
    if (valid && q == 0) {
        float b = ((r == 0) ? b1 : (r == 1) ? b2 : b3)[0];
        ys[pl] = (acc / (denom + 1e-16f) + b) * ln_w[r];
    }
    __syncthreads();
    if (valid && q == 0 && r == 0)
        out[n] = ys[pl] + ys[pl + 1] + ys[pl + 2] + ln_b[0];
}

extern "C" void kernel_launch(void* const* d_in, const int* in_sizes, int n_in,
                              void* d_out, int out_size, void* d_ws, size_t ws_size,
                              hipStream_t stream) {
    const float* X  = (const float*)d_in[0];
    const int*   A1 = (const int*)d_in[1];
    const int*   A2 = (const int*)d_in[2];
    const int*   A3 = (const int*)d_in[3];
    const float* W11 = (const float*)d_in[5];
    const float* as11 = (const float*)d_in[6];
    const float* ad11 = (const float*)d_in[7];
    const float* b11 = (const float*)d_in[8];
    const float* W12 = (const float*)d_in[9];
    const float* as12 = (const float*)d_in[10];
    const float* ad12 = (const float*)d_in[11];
    const float* b12 = (const float*)d_in[12];
    const float* W21 = (const float*)d_in[13];
    const float* as21 = (const float*)d_in[14];
    const float* ad21 = (const float*)d_in[15];
    const float* b21 = (const float*)d_in[16];
    const float* W22 = (const float*)d_in[17];
    const float* as22 = (const float*)d_in[18];
    const float* ad22 = (const float*)d_in[19];
    const float* b22 = (const float*)d_in[20];
    const float* W31 = (const float*)d_in[21];
    const float* as31 = (const float*)d_in[22];
    const float* ad31 = (const float*)d_in[23];
    const float* b31 = (const float*)d_in[24];
    const float* W32 = (const float*)d_in[25];
    const float* as32 = (const float*)d_in[26];
    const float* ad32 = (const float*)d_in[27];
    const float* b32 = (const float*)d_in[28];
    const float* ln_w = (const float*)d_in[29];
    const float* ln_b = (const float*)d_in[30];

    const int N = in_sizes[0] / 64;
    const int E = in_sizes[1] / 2;
    const int total = 3 * N;
    const int nbA = (total + 1023) / 1024;

    // workspace layout
    float* w = (float*)d_ws;
    float* s_src1 = w; w += (size_t)N * 24;
    float* s_dst1 = w; w += (size_t)N * 24;
    float* h2     = w; w += (size_t)N * 3;
    unsigned short* h_bf = (unsigned short*)w; w += (size_t)N * 192;  // N*384 bf16
    unsigned short* Xc   = (unsigned short*)w; w += (size_t)N * 192;  // N*384 bf16
    int* iw     = (int*)w;
    int* deg    = iw; iw += (size_t)3 * N;
    int* start  = iw; iw += (size_t)3 * N;
    int* bsum   = iw; iw += 1024;
    int* deg8   = iw; iw += (size_t)24 * N;
    int* startk = iw; iw += (size_t)24 * N;
    int* epos   = iw; iw += (size_t)3 * E;
    int* csr    = iw; iw += (size_t)3 * E;

    const int BLK = 256;

    // ---- CSR build (shared by both layers) ----
    hipMemsetAsync(deg8, 0, (size_t)24 * N * sizeof(int), stream);
    {
        dim3 grid((E + BLK - 1) / BLK, 3);
        k_degpos8<<<grid, BLK, 0, stream>>>(A1, A2, A3, deg8, epos, E, N);
        k_scanA2<<<nbA, 256, 0, stream>>>(deg8, deg, startk, start, bsum, total, N);
        k_scanB<<<1, 256, 0, stream>>>(bsum, nbA);
        k_scanC2<<<(total + BLK - 1) / BLK, BLK, 0, stream>>>(start, bsum, startk, total, N, E);
        k_scatter2<<<grid, BLK, 0, stream>>>(A1, A2, A3, startk, epos, csr, E, N);
    }

    // ---- layer 1 ----
    k_linear1<<<(N + L1_NODES - 1) / L1_NODES, 384, 0, stream>>>(
        X, W11, W21, W31, as11, ad11, as21, ad21, as31, ad31,
        h_bf, s_src1, s_dst1, N);
    {
        dim3 grid(N, 3);
        k_agg1<<<grid, 64, 0, stream>>>(h_bf, s_src1, s_dst1, deg, start, csr,
                                        b11, b21, b31, Xc, E, N);
    }

    // ---- layer 2 ----
    k_linear2<<<(N + 15) / 16, 1024, 0, stream>>>(Xc, W12, W22, W32, h2, N);
    {
        int nb = (total + 47) / 48;
        k_agg2f<<<nb, 384, 0, stream>>>(
            h2, deg, start, csr,
            as12, ad12, as22, ad22, as32, ad32,
            b12, b22, b32, ln_w, ln_b, (float*)d_out, E, N);
    }
}

// Round 12
// 427.944 us; speedup vs baseline: 1.0614x; 1.0614x over previous
//
#include <hip/hip_runtime.h>
#include <cstdint>
#include <cstddef>

#define NEG_SLOPE 0.2f

__device__ __forceinline__ float lrelu(float v) { return v >= 0.f ? v : NEG_SLOPE * v; }

// bf16 pack/unpack (round-to-nearest-even)
__device__ __forceinline__ unsigned short f2bf(float x) {
    union { float f; uint32_t u; } v; v.f = x;
    uint32_t r = v.u + 0x7FFFu + ((v.u >> 16) & 1u);
    return (unsigned short)(r >> 16);
}
__device__ __forceinline__ float bf2f_lo(uint32_t u) {
    union { uint32_t u; float f; } v; v.u = u << 16;
    return v.f;
}
__device__ __forceinline__ float bf2f_hi(uint32_t u) {
    union { uint32_t u; float f; } v; v.u = u & 0xFFFF0000u;
    return v.f;
}

// ==================== CSR build ====================
// pass 1: 8-way-spread degree count; atomic return = slot within (dst, copy k)
__global__ void k_degpos8(const int* __restrict__ A1, const int* __restrict__ A2,
                          const int* __restrict__ A3, int* __restrict__ deg8,
                          unsigned short* __restrict__ epos, int E, int N) {
    int e = blockIdx.x * blockDim.x + threadIdx.x;
    if (e >= E) return;
    int r = blockIdx.y;
    int k = blockIdx.x & 7;
    const int* A = (r == 0) ? A1 : (r == 1) ? A2 : A3;
    int dst = A[E + e];
    epos[(size_t)r * E + e] =
        (unsigned short)atomicAdd(&deg8[(size_t)((r << 3) + k) * N + dst], 1);
}

// scan A: fold 8 sub-histograms -> deg + per-copy local offsets (startk, pre-base),
// plus block-local exclusive scan of deg -> start, block sums -> bsum
__global__ void k_scanA2(const int* __restrict__ deg8, int* __restrict__ deg,
                         int* __restrict__ startk, int* __restrict__ start,
                         int* __restrict__ bsum, int total, int N) {
    __shared__ int tmp[256];
    int t = threadIdx.x;
    int base = blockIdx.x * 1024 + t * 4;
    int v[4]; int s = 0;
    #pragma unroll
    for (int m = 0; m < 4; ++m) {
        int g = base + m;
        int sum8 = 0;
        if (g < total) {
            int r = g / N;
            int n = g - r * N;
            #pragma unroll
            for (int k = 0; k < 8; ++k) {
                size_t idx = (size_t)((r << 3) + k) * N + n;
                int dv = deg8[idx];
                startk[idx] = sum8;
                sum8 += dv;
            }
            deg[g] = sum8;
        }
        v[m] = sum8; s += sum8;
    }
    tmp[t] = s; __syncthreads();
    for (int off = 1; off < 256; off <<= 1) {
        int x = (t >= off) ? tmp[t - off] : 0; __syncthreads();
        tmp[t] += x; __syncthreads();
    }
    int run = tmp[t] - s;
    #pragma unroll
    for (int m = 0; m < 4; ++m) {
        if (base + m < total) start[base + m] = run;
        run += v[m];
    }
    if (t == 255) bsum[blockIdx.x] = tmp[255];
}

// scan B: one block, exclusive scan of block sums
__global__ void k_scanB(int* __restrict__ bsum, int nb) {
    __shared__ int tmp[256];
    int t = threadIdx.x;
    int v[4]; int s = 0;
    #pragma unroll
    for (int k = 0; k < 4; ++k) { int i = t * 4 + k; v[k] = (i < nb) ? bsum[i] : 0; s += v[k]; }
    tmp[t] = s; __syncthreads();
    for (int off = 1; off < 256; off <<= 1) {
        int x = (t >= off) ? tmp[t - off] : 0; __syncthreads();
        tmp[t] += x; __syncthreads();
    }
    int run = tmp[t] - s;
    #pragma unroll
    for (int k = 0; k < 4; ++k) {
        int i = t * 4 + k;
        if (i < nb) { int vv = v[k]; bsum[i] = run; run += vv; }
    }
}

// scan C: finalize global base; push base into the 8 startk copies
__global__ void k_scanC2(int* __restrict__ start, const int* __restrict__ bsum,
                         int* __restrict__ startk, int total, int N, int E) {
    int g = blockIdx.x * blockDim.x + threadIdx.x;
    if (g >= total) return;
    int r = g / N;
    int n = g - r * N;
    int base = start[g] + bsum[g >> 10] - r * E;
    start[g] = base;
    #pragma unroll
    for (int k = 0; k < 8; ++k)
        startk[(size_t)((r << 3) + k) * N + n] += base;
}

// pass 2: no atomics — pos = startk[k][dst] + epos; csr is ushort (src < 65536)
__global__ void k_scatter2(const int* __restrict__ A1, const int* __restrict__ A2,
                           const int* __restrict__ A3,
                           const int* __restrict__ startk,
                           const unsigned short* __restrict__ epos,
                           unsigned short* __restrict__ csr, int E, int N) {
    int e = blockIdx.x * blockDim.x + threadIdx.x;
    if (e >= E) return;
    int r = blockIdx.y;
    int k = blockIdx.x & 7;
    const int* A = (r == 0) ? A1 : (r == 1) ? A2 : A3;
    int src = A[e], dst = A[E + e];
    int pos = startk[(size_t)((r << 3) + k) * N + dst] + epos[(size_t)r * E + e];
    csr[(size_t)r * E + pos] = (unsigned short)src;
}

// ==================== layer 1: register-W linear + scores ====================
#define L1_NODES 64
__global__ __launch_bounds__(384) void k_linear1(
        const float* __restrict__ X,
        const float* __restrict__ W1, const float* __restrict__ W2,
        const float* __restrict__ W3,
        const float* __restrict__ as1, const float* __restrict__ ad1,
        const float* __restrict__ as2, const float* __restrict__ ad2,
        const float* __restrict__ as3, const float* __restrict__ ad3,
        unsigned short* __restrict__ h_bf,
        float* __restrict__ s_src, float* __restrict__ s_dst, int N) {
    __shared__ float Xs[L1_NODES][64];
    int t = threadIdx.x;
    int n0 = blockIdx.x * L1_NODES;
    {
        const float4* X4 = reinterpret_cast<const float4*>(X);
        float4* Xs4 = reinterpret_cast<float4*>(&Xs[0][0]);
        for (int i = t; i < L1_NODES * 16; i += 384) {
            int nl = i >> 4;
            float4 xv = make_float4(0.f, 0.f, 0.f, 0.f);
            if (n0 + nl < N) xv = X4[(size_t)(n0 + nl) * 16 + (i & 15)];
            Xs4[i] = xv;
        }
    }
    int r = t >> 7, col = t & 127, head = (t >> 4) & 7, c = t & 15;
    const float* Wp = ((r == 0) ? W1 : (r == 1) ? W2 : W3) + col;
    float Wc[64];
    #pragma unroll
    for (int k = 0; k < 64; ++k) Wc[k] = Wp[(size_t)k * 128];
    float as_v = ((r == 0) ? as1 : (r == 1) ? as2 : as3)[head * 16 + c];
    float ad_v = ((r == 0) ? ad1 : (r == 1) ? ad2 : ad3)[head * 16 + c];
    __syncthreads();
    int nmax = min(L1_NODES, N - n0);
    int rh = (r << 3) + head;
    for (int n = 0; n < nmax; ++n) {
        const float4* xr = reinterpret_cast<const float4*>(&Xs[n][0]);
        float a0 = 0.f, a1 = 0.f, a2 = 0.f, a3 = 0.f;
        #pragma unroll
        for (int k4 = 0; k4 < 16; ++k4) {
            float4 xv = xr[k4];
            a0 = fmaf(xv.x, Wc[k4 * 4 + 0], a0);
            a1 = fmaf(xv.y, Wc[k4 * 4 + 1], a1);
            a2 = fmaf(xv.z, Wc[k4 * 4 + 2], a2);
            a3 = fmaf(xv.w, Wc[k4 * 4 + 3], a3);
        }
        float acc = (a0 + a1) + (a2 + a3);
        h_bf[(size_t)(n0 + n) * 384 + t] = f2bf(acc);
        float ss = acc * as_v, sd = acc * ad_v;
        ss += __shfl_xor(ss, 1); ss += __shfl_xor(ss, 2);
        ss += __shfl_xor(ss, 4); ss += __shfl_xor(ss, 8);
        sd += __shfl_xor(sd, 1); sd += __shfl_xor(sd, 2);
        sd += __shfl_xor(sd, 4); sd += __shfl_xor(sd, 8);
        if (c == 0) {
            s_src[(size_t)(n0 + n) * 24 + rh] = ss;
            s_dst[(size_t)(n0 + n) * 24 + rh] = sd;
        }
    }
}

// ==================== layer-1 aggregation + fused layer-2 linear ====================
// block = (dst n, branch r), 64 threads (one wave); thread owns a uint = 2 bf16 ch.
// Epilogue: Xc never materialized; 3 partial dots with W2 wave-reduced, atomicAdd h2.
__global__ __launch_bounds__(64) void k_agg1(
        const unsigned short* __restrict__ h_bf,
        const float* __restrict__ s_src, const float* __restrict__ s_dst,
        const int* __restrict__ deg, const int* __restrict__ start,
        const unsigned short* __restrict__ csr,
        const float* __restrict__ b1, const float* __restrict__ b2,
        const float* __restrict__ b3,
        const float* __restrict__ W12, const float* __restrict__ W22,
        const float* __restrict__ W32,
        float* __restrict__ h2, int E, int N) {
    __shared__ int sidx[64];
    __shared__ float sex[64 * 8];
    int n = blockIdx.x;
    int r = blockIdx.y;
    int j = threadIdx.x;              // uint channel-pair index 0..63
    int h = j >> 3;                   // head (16 ch = 8 uints per head)
    int rh = r * 8 + h;
    int s0 = start[(size_t)r * N + n];
    int d  = deg[(size_t)r * N + n];
    const uint32_t* hb = reinterpret_cast<const uint32_t*>(h_bf);
    int off = r * 64 + j;
    float sd = s_dst[(size_t)n * 24 + rh];
    float ex0 = __expf(lrelu(s_src[(size_t)n * 24 + rh] + sd));
    float denom = ex0;
    uint32_t hv0 = hb[(size_t)n * 192 + off];
    float accx = ex0 * bf2f_lo(hv0);
    float accy = ex0 * bf2f_hi(hv0);
    int hA = j & 7;
    float sdA = s_dst[(size_t)n * 24 + r * 8 + hA];
    const unsigned short* cs = csr + (size_t)r * E + s0;
    for (int c0 = 0; c0 < d; c0 += 64) {
        int dc = min(64, d - c0);
        if (j < dc) sidx[j] = cs[c0 + j];
        __syncthreads();
        // phase A: one exp per (neighbor, head)
        for (int p = j; p < dc * 8; p += 64) {
            int i = p >> 3;
            float ssv = s_src[(size_t)sidx[i] * 24 + r * 8 + hA];
            sex[p] = __expf(lrelu(ssv + sdA));
        }
        __syncthreads();
        // phase B: gather + accumulate (one uint = 2 bf16 per thread, 256B/wave/neighbor)
        for (int i = 0; i < dc; ++i) {
            float ex = sex[i * 8 + h];
            uint32_t hv = hb[(size_t)sidx[i] * 192 + off];
            denom += ex;
            accx = fmaf(ex, bf2f_lo(hv), accx);
            accy = fmaf(ex, bf2f_hi(hv), accy);
        }
        __syncthreads();
    }
    const float* b = (r == 0) ? b1 : (r == 1) ? b2 : b3;
    float inv = 1.0f / (denom + 1e-16f);
    float ox = accx * inv + b[2 * j];
    float oy = accy * inv + b[2 * j + 1];
    ox = (ox > 0.f) ? ox : 0.f;
    oy = (oy > 0.f) ? oy : 0.f;
    // fused layer-2 linear: partial dots over this block's 128 channels
    int cbase = r * 128 + 2 * j;
    float p0 = ox * W12[cbase] + oy * W12[cbase + 1];
    float p1 = ox * W22[cbase] + oy * W22[cbase + 1];
    float p2 = ox * W32[cbase] + oy * W32[cbase + 1];
    #pragma unroll
    for (int o = 32; o > 0; o >>= 1) {
        p0 += __shfl_xor(p0, o);
        p1 += __shfl_xor(p1, o);
        p2 += __shfl_xor(p2, o);
    }
    if (j == 0) {
        atomicAdd(&h2[(size_t)n * 3 + 0], p0);
        atomicAdd(&h2[(size_t)n * 3 + 1], p1);
        atomicAdd(&h2[(size_t)n * 3 + 2], p2);
    }
}

// ==================== layer-2 aggregation + final projection ====================
// 8 lanes per (node, branch); blockDim 384 = 48 units = 16 nodes
__global__ __launch_bounds__(384) void k_agg2f(
        const float* __restrict__ h2,
        const int* __restrict__ deg, const int* __restrict__ start,
        const unsigned short* __restrict__ csr,
        const float* __restrict__ as1, const float* __restrict__ ad1,
        const float* __restrict__ as2, const float* __restrict__ ad2,
        const float* __restrict__ as3, const float* __restrict__ ad3,
        const float* __restrict__ b1, const float* __restrict__ b2,
        const float* __restrict__ b3,
        const float* __restrict__ ln_w, const float* __restrict__ ln_b,
        float* __restrict__ out, int E, int N) {
    __shared__ float ys[48];
    int tl = threadIdx.x;
    int pl = tl >> 3;                 // unit 0..47
    int q  = tl & 7;                  // lane in unit
    int id = blockIdx.x * 48 + pl;
    bool valid = id < 3 * N;
    int n = id / 3;
    int r = id - 3 * n;
    float denom = 0.f, acc = 0.f;
    if (valid) {
        float a_s = ((r == 0) ? as1 : (r == 1) ? as2 : as3)[0];
        float a_d = ((r == 0) ? ad1 : (r == 1) ? ad2 : ad3)[0];
        int s0 = start[(size_t)r * N + n];
        int d  = deg[(size_t)r * N + n];
        float hd = h2[id];
        float sd = a_d * hd;
        const unsigned short* cs = csr + (size_t)r * E + s0;
        for (int i = q; i < d; i += 8) {
            float hs = h2[(size_t)cs[i] * 3 + r];
            float e2 = __expf(lrelu(fmaf(a_s, hs, sd)));
            denom += e2;
            acc = fmaf(e2, hs, acc);
        }
        if (q == 0) {
            float ev = __expf(lrelu(fmaf(a_s, hd, sd)));
            denom += ev;
            acc = fmaf(ev, hd, acc);
        }
    }
    denom += __shfl_xor(denom, 1); denom += __shfl_xor(denom, 2); denom += __shfl_xor(denom, 4);
    acc   += __shfl_xor(acc, 1);   acc   += __shfl_xor(acc, 2);   acc   += __shfl_xor(acc, 4);
    if (valid && q == 0) {
        float b = ((r == 0) ? b1 : (r == 1) ? b2 : b3)[0];
        ys[pl] = (acc / (denom + 1e-16f) + b) * ln_w[r];
    }
    __syncthreads();
    if (valid && q == 0 && r == 0)
        out[n] = ys[pl] + ys[pl + 1] + ys[pl + 2] + ln_b[0];
}

extern "C" void kernel_launch(void* const* d_in, const int* in_sizes, int n_in,
                              void* d_out, int out_size, void* d_ws, size_t ws_size,
                              hipStream_t stream) {
    const float* X  = (const float*)d_in[0];
    const int*   A1 = (const int*)d_in[1];
    const int*   A2 = (const int*)d_in[2];
    const int*   A3 = (const int*)d_in[3];
    const float* W11 = (const float*)d_in[5];
    const float* as11 = (const float*)d_in[6];
    const float* ad11 = (const float*)d_in[7];
    const float* b11 = (const float*)d_in[8];
    const float* W12 = (const float*)d_in[9];
    const float* as12 = (const float*)d_in[10];
    const float* ad12 = (const float*)d_in[11];
    const float* b12 = (const float*)d_in[12];
    const float* W21 = (const float*)d_in[13];
    const float* as21 = (const float*)d_in[14];
    const float* ad21 = (const float*)d_in[15];
    const float* b21 = (const float*)d_in[16];
    const float* W22 = (const float*)d_in[17];
    const float* as22 = (const float*)d_in[18];
    const float* ad22 = (const float*)d_in[19];
    const float* b22 = (const float*)d_in[20];
    const float* W31 = (const float*)d_in[21];
    const float* as31 = (const float*)d_in[22];
    const float* ad31 = (const float*)d_in[23];
    const float* b31 = (const float*)d_in[24];
    const float* W32 = (const float*)d_in[25];
    const float* as32 = (const float*)d_in[26];
    const float* ad32 = (const float*)d_in[27];
    const float* b32 = (const float*)d_in[28];
    const float* ln_w = (const float*)d_in[29];
    const float* ln_b = (const float*)d_in[30];

    const int N = in_sizes[0] / 64;
    const int E = in_sizes[1] / 2;
    const int total = 3 * N;
    const int nbA = (total + 1023) / 1024;

    // workspace layout
    float* w = (float*)d_ws;
    float* s_src1 = w; w += (size_t)N * 24;
    float* s_dst1 = w; w += (size_t)N * 24;
    float* h2     = w; w += (size_t)N * 3;
    unsigned short* h_bf = (unsigned short*)w; w += (size_t)N * 192;  // N*384 bf16
    int* iw     = (int*)w;
    int* deg    = iw; iw += (size_t)3 * N;
    int* start  = iw; iw += (size_t)3 * N;
    int* bsum   = iw; iw += 1024;
    int* deg8   = iw; iw += (size_t)24 * N;
    int* startk = iw; iw += (size_t)24 * N;
    unsigned short* epos = (unsigned short*)iw;
    unsigned short* csr  = epos + (size_t)3 * E;

    const int BLK = 256;

    // ---- CSR build (shared by both layers) + zero h2 accumulator ----
    hipMemsetAsync(deg8, 0, (size_t)24 * N * sizeof(int), stream);
    hipMemsetAsync(h2, 0, (size_t)3 * N * sizeof(float), stream);
    {
        dim3 grid((E + BLK - 1) / BLK, 3);
        k_degpos8<<<grid, BLK, 0, stream>>>(A1, A2, A3, deg8, epos, E, N);
        k_scanA2<<<nbA, 256, 0, stream>>>(deg8, deg, startk, start, bsum, total, N);
        k_scanB<<<1, 256, 0, stream>>>(bsum, nbA);
        k_scanC2<<<(total + BLK - 1) / BLK, BLK, 0, stream>>>(start, bsum, startk, total, N, E);
        k_scatter2<<<grid, BLK, 0, stream>>>(A1, A2, A3, startk, epos, csr, E, N);
    }

    // ---- layer 1 (+ fused layer-2 linear in agg1 epilogue) ----
    k_linear1<<<(N + L1_NODES - 1) / L1_NODES, 384, 0, stream>>>(
        X, W11, W21, W31, as11, ad11, as21, ad21, as31, ad31,
        h_bf, s_src1, s_dst1, N);
    {
        dim3 grid(N, 3);
        k_agg1<<<grid, 64, 0, stream>>>(h_bf, s_src1, s_dst1, deg, start, csr,
                                        b11, b21, b31, W12, W22, W32, h2, E, N);
    }

    // ---- layer 2 aggregation + final projection ----
    {
        int nb = (total + 47) / 48;
        k_agg2f<<<nb, 384, 0, stream>>>(
            h2, deg, start, csr,
            as12, ad12, as22, ad22, as32, ad32,
            b12, b22, b32, ln_w, ln_b, (float*)d_out, E, N);
    }
}

// Round 13
// 373.092 us; speedup vs baseline: 1.2174x; 1.1470x over previous
//
#include <hip/hip_runtime.h>
#include <cstdint>
#include <cstddef>

#define NEG_SLOPE 0.2f

__device__ __forceinline__ float lrelu(float v) { return v >= 0.f ? v : NEG_SLOPE * v; }

// bf16 pack/unpack (round-to-nearest-even)
__device__ __forceinline__ unsigned short f2bf(float x) {
    union { float f; uint32_t u; } v; v.f = x;
    uint32_t r = v.u + 0x7FFFu + ((v.u >> 16) & 1u);
    return (unsigned short)(r >> 16);
}
__device__ __forceinline__ float bf2f_lo(uint32_t u) {
    union { uint32_t u; float f; } v; v.u = u << 16;
    return v.f;
}
__device__ __forceinline__ float bf2f_hi(uint32_t u) {
    union { uint32_t u; float f; } v; v.u = u & 0xFFFF0000u;
    return v.f;
}

// spread-copy index: derived from e only, so degpos and scatter always agree
__device__ __forceinline__ int spreadk(int e) { return (e >> 8) & 7; }

#define L1_NODES 64

// ==================== fused: layer-1 linear/scores  ∥  degree count ====================
// blocks [0, nL1): linear1 tiles (384 thr = one W column each, 64-node tile)
// blocks [nL1, nL1+3*nbE): degpos — 8-way-spread degree histogram + slot epos
__global__ __launch_bounds__(384) void k_lin1_deg(
        const float* __restrict__ X,
        const float* __restrict__ W1, const float* __restrict__ W2,
        const float* __restrict__ W3,
        const float* __restrict__ as1, const float* __restrict__ ad1,
        const float* __restrict__ as2, const float* __restrict__ ad2,
        const float* __restrict__ as3, const float* __restrict__ ad3,
        unsigned short* __restrict__ h_bf,
        float* __restrict__ s_src, float* __restrict__ s_dst,
        const int* __restrict__ A1, const int* __restrict__ A2,
        const int* __restrict__ A3,
        int* __restrict__ deg8, unsigned short* __restrict__ epos,
        int nL1, int nbE, int E, int N) {
    int t = threadIdx.x;
    if (blockIdx.x >= nL1) {
        // ---- degpos path ----
        int b = blockIdx.x - nL1;
        int r = b / nbE;
        int e = (b - r * nbE) * 384 + t;
        if (e < E) {
            const int* A = (r == 0) ? A1 : (r == 1) ? A2 : A3;
            int dst = A[E + e];
            epos[(size_t)r * E + e] =
                (unsigned short)atomicAdd(&deg8[(size_t)((r << 3) + spreadk(e)) * N + dst], 1);
        }
        return;
    }
    // ---- linear1 path ----
    __shared__ float Xs[L1_NODES][64];
    int n0 = blockIdx.x * L1_NODES;
    {
        const float4* X4 = reinterpret_cast<const float4*>(X);
        float4* Xs4 = reinterpret_cast<float4*>(&Xs[0][0]);
        for (int i = t; i < L1_NODES * 16; i += 384) {
            int nl = i >> 4;
            float4 xv = make_float4(0.f, 0.f, 0.f, 0.f);
            if (n0 + nl < N) xv = X4[(size_t)(n0 + nl) * 16 + (i & 15)];
            Xs4[i] = xv;
        }
    }
    int r = t >> 7, col = t & 127, head = (t >> 4) & 7, c = t & 15;
    const float* Wp = ((r == 0) ? W1 : (r == 1) ? W2 : W3) + col;
    float Wc[64];
    #pragma unroll
    for (int k = 0; k < 64; ++k) Wc[k] = Wp[(size_t)k * 128];
    float as_v = ((r == 0) ? as1 : (r == 1) ? as2 : as3)[head * 16 + c];
    float ad_v = ((r == 0) ? ad1 : (r == 1) ? ad2 : ad3)[head * 16 + c];
    __syncthreads();
    int nmax = min(L1_NODES, N - n0);
    int rh = (r << 3) + head;
    for (int n = 0; n < nmax; ++n) {
        const float4* xr = reinterpret_cast<const float4*>(&Xs[n][0]);
        float a0 = 0.f, a1 = 0.f, a2 = 0.f, a3 = 0.f;
        #pragma unroll
        for (int k4 = 0; k4 < 16; ++k4) {
            float4 xv = xr[k4];
            a0 = fmaf(xv.x, Wc[k4 * 4 + 0], a0);
            a1 = fmaf(xv.y, Wc[k4 * 4 + 1], a1);
            a2 = fmaf(xv.z, Wc[k4 * 4 + 2], a2);
            a3 = fmaf(xv.w, Wc[k4 * 4 + 3], a3);
        }
        float acc = (a0 + a1) + (a2 + a3);
        h_bf[(size_t)(n0 + n) * 384 + t] = f2bf(acc);
        float ss = acc * as_v, sd = acc * ad_v;
        ss += __shfl_xor(ss, 1); ss += __shfl_xor(ss, 2);
        ss += __shfl_xor(ss, 4); ss += __shfl_xor(ss, 8);
        sd += __shfl_xor(sd, 1); sd += __shfl_xor(sd, 2);
        sd += __shfl_xor(sd, 4); sd += __shfl_xor(sd, 8);
        if (c == 0) {
            s_src[(size_t)(n0 + n) * 24 + rh] = ss;
            s_dst[(size_t)(n0 + n) * 24 + rh] = sd;
        }
    }
}

// ==================== CSR scans ====================
__global__ void k_scanA2(const int* __restrict__ deg8, int* __restrict__ deg,
                         int* __restrict__ startk, int* __restrict__ start,
                         int* __restrict__ bsum, int total, int N) {
    __shared__ int tmp[256];
    int t = threadIdx.x;
    int base = blockIdx.x * 1024 + t * 4;
    int v[4]; int s = 0;
    #pragma unroll
    for (int m = 0; m < 4; ++m) {
        int g = base + m;
        int sum8 = 0;
        if (g < total) {
            int r = g / N;
            int n = g - r * N;
            #pragma unroll
            for (int k = 0; k < 8; ++k) {
                size_t idx = (size_t)((r << 3) + k) * N + n;
                int dv = deg8[idx];
                startk[idx] = sum8;
                sum8 += dv;
            }
            deg[g] = sum8;
        }
        v[m] = sum8; s += sum8;
    }
    tmp[t] = s; __syncthreads();
    for (int off = 1; off < 256; off <<= 1) {
        int x = (t >= off) ? tmp[t - off] : 0; __syncthreads();
        tmp[t] += x; __syncthreads();
    }
    int run = tmp[t] - s;
    #pragma unroll
    for (int m = 0; m < 4; ++m) {
        if (base + m < total) start[base + m] = run;
        run += v[m];
    }
    if (t == 255) bsum[blockIdx.x] = tmp[255];
}

__global__ void k_scanB(int* __restrict__ bsum, int nb) {
    __shared__ int tmp[256];
    int t = threadIdx.x;
    int v[4]; int s = 0;
    #pragma unroll
    for (int k = 0; k < 4; ++k) { int i = t * 4 + k; v[k] = (i < nb) ? bsum[i] : 0; s += v[k]; }
    tmp[t] = s; __syncthreads();
    for (int off = 1; off < 256; off <<= 1) {
        int x = (t >= off) ? tmp[t - off] : 0; __syncthreads();
        tmp[t] += x; __syncthreads();
    }
    int run = tmp[t] - s;
    #pragma unroll
    for (int k = 0; k < 4; ++k) {
        int i = t * 4 + k;
        if (i < nb) { int vv = v[k]; bsum[i] = run; run += vv; }
    }
}

// scan C: finalize global base; push base into the 8 startk copies; zero h2
__global__ void k_scanC2(int* __restrict__ start, const int* __restrict__ bsum,
                         int* __restrict__ startk, float* __restrict__ h2,
                         int total, int N, int E) {
    int g = blockIdx.x * blockDim.x + threadIdx.x;
    if (g >= total) return;
    h2[g] = 0.f;
    int r = g / N;
    int n = g - r * N;
    int base = start[g] + bsum[g >> 10] - r * E;
    start[g] = base;
    #pragma unroll
    for (int k = 0; k < 8; ++k)
        startk[(size_t)((r << 3) + k) * N + n] += base;
}

// scatter: no atomics — pos = startk[k(e)][dst] + epos
__global__ void k_scatter2(const int* __restrict__ A1, const int* __restrict__ A2,
                           const int* __restrict__ A3,
                           const int* __restrict__ startk,
                           const unsigned short* __restrict__ epos,
                           unsigned short* __restrict__ csr, int E, int N) {
    int e = blockIdx.x * blockDim.x + threadIdx.x;
    if (e >= E) return;
    int r = blockIdx.y;
    const int* A = (r == 0) ? A1 : (r == 1) ? A2 : A3;
    int src = A[e], dst = A[E + e];
    int pos = startk[(size_t)((r << 3) + spreadk(e)) * N + dst] + epos[(size_t)r * E + e];
    csr[(size_t)r * E + pos] = (unsigned short)src;
}

// ==================== layer-1 aggregation + fused layer-2 linear ====================
__global__ __launch_bounds__(64) void k_agg1(
        const unsigned short* __restrict__ h_bf,
        const float* __restrict__ s_src, const float* __restrict__ s_dst,
        const int* __restrict__ deg, const int* __restrict__ start,
        const unsigned short* __restrict__ csr,
        const float* __restrict__ b1, const float* __restrict__ b2,
        const float* __restrict__ b3,
        const float* __restrict__ W12, const float* __restrict__ W22,
        const float* __restrict__ W32,
        float* __restrict__ h2, int E, int N) {
    __shared__ int sidx[64];
    __shared__ float sex[64 * 8];
    int n = blockIdx.x;
    int r = blockIdx.y;
    int j = threadIdx.x;              // uint channel-pair index 0..63
    int h = j >> 3;                   // head (16 ch = 8 uints per head)
    int rh = r * 8 + h;
    int s0 = start[(size_t)r * N + n];
    int d  = deg[(size_t)r * N + n];
    const uint32_t* hb = reinterpret_cast<const uint32_t*>(h_bf);
    int off = r * 64 + j;
    float sd = s_dst[(size_t)n * 24 + rh];
    float ex0 = __expf(lrelu(s_src[(size_t)n * 24 + rh] + sd));
    float denom = ex0;
    uint32_t hv0 = hb[(size_t)n * 192 + off];
    float accx = ex0 * bf2f_lo(hv0);
    float accy = ex0 * bf2f_hi(hv0);
    int hA = j & 7;
    float sdA = s_dst[(size_t)n * 24 + r * 8 + hA];
    const unsigned short* cs = csr + (size_t)r * E + s0;
    for (int c0 = 0; c0 < d; c0 += 64) {
        int dc = min(64, d - c0);
        if (j < dc) sidx[j] = cs[c0 + j];
        __syncthreads();
        // phase A: one exp per (neighbor, head)
        for (int p = j; p < dc * 8; p += 64) {
            int i = p >> 3;
            float ssv = s_src[(size_t)sidx[i] * 24 + r * 8 + hA];
            sex[p] = __expf(lrelu(ssv + sdA));
        }
        __syncthreads();
        // phase B: gather + accumulate (one uint = 2 bf16 per thread, 256B/wave/neighbor)
        for (int i = 0; i < dc; ++i) {
            float ex = sex[i * 8 + h];
            uint32_t hv = hb[(size_t)sidx[i] * 192 + off];
            denom += ex;
            accx = fmaf(ex, bf2f_lo(hv), accx);
            accy = fmaf(ex, bf2f_hi(hv), accy);
        }
        __syncthreads();
    }
    const float* b = (r == 0) ? b1 : (r == 1) ? b2 : b3;
    float inv = 1.0f / (denom + 1e-16f);
    float ox = accx * inv + b[2 * j];
    float oy = accy * inv + b[2 * j + 1];
    ox = (ox > 0.f) ? ox : 0.f;
    oy = (oy > 0.f) ? oy : 0.f;
    // fused layer-2 linear: partial dots over this block's 128 channels
    int cbase = r * 128 + 2 * j;
    float p0 = ox * W12[cbase] + oy * W12[cbase + 1];
    float p1 = ox * W22[cbase] + oy * W22[cbase + 1];
    float p2 = ox * W32[cbase] + oy * W32[cbase + 1];
    #pragma unroll
    for (int o = 32; o > 0; o >>= 1) {
        p0 += __shfl_xor(p0, o);
        p1 += __shfl_xor(p1, o);
        p2 += __shfl_xor(p2, o);
    }
    if (j == 0) {
        atomicAdd(&h2[(size_t)n * 3 + 0], p0);
        atomicAdd(&h2[(size_t)n * 3 + 1], p1);
        atomicAdd(&h2[(size_t)n * 3 + 2], p2);
    }
}

// ==================== layer-2 aggregation + final projection ====================
__global__ __launch_bounds__(384) void k_agg2f(
        const float* __restrict__ h2,
        const int* __restrict__ deg, const int* __restrict__ start,
        const unsigned short* __restrict__ csr,
        const float* __restrict__ as1, const float* __restrict__ ad1,
        const float* __restrict__ as2, const float* __restrict__ ad2,
        const float* __restrict__ as3, const float* __restrict__ ad3,
        const float* __restrict__ b1, const float* __restrict__ b2,
        const float* __restrict__ b3,
        const float* __restrict__ ln_w, const float* __restrict__ ln_b,
        float* __restrict__ out, int E, int N) {
    __shared__ float ys[48];
    int tl = threadIdx.x;
    int pl = tl >> 3;                 // unit 0..47
    int q  = tl & 7;                  // lane in unit
    int id = blockIdx.x * 48 + pl;
    bool valid = id < 3 * N;
    int n = id / 3;
    int r = id - 3 * n;
    float denom = 0.f, acc = 0.f;
    if (valid) {
        float a_s = ((r == 0) ? as1 : (r == 1) ? as2 : as3)[0];
        float a_d = ((r == 0) ? ad1 : (r == 1) ? ad2 : ad3)[0];
        int s0 = start[(size_t)r * N + n];
        int d  = deg[(size_t)r * N + n];
        float hd = h2[id];
        float sd = a_d * hd;
        const unsigned short* cs = csr + (size_t)r * E + s0;
        for (int i = q; i < d; i += 8) {
            float hs = h2[(size_t)cs[i] * 3 + r];
            float e2 = __expf(lrelu(fmaf(a_s, hs, sd)));
            denom += e2;
            acc = fmaf(e2, hs, acc);
        }
        if (q == 0) {
            float ev = __expf(lrelu(fmaf(a_s, hd, sd)));
            denom += ev;
            acc = fmaf(ev, hd, acc);
        }
    }
    denom += __shfl_xor(denom, 1); denom += __shfl_xor(denom, 2); denom += __shfl_xor(denom, 4);
    acc   += __shfl_xor(acc, 1);   acc   += __shfl_xor(acc, 2);   acc   += __shfl_xor(acc, 4);
    if (valid && q == 0) {
        float b = ((r == 0) ? b1 : (r == 1) ? b2 : b3)[0];
        ys[pl] = (acc / (denom + 1e-16f) + b) * ln_w[r];
    }
    __syncthreads();
    if (valid && q == 0 && r == 0)
        out[n] = ys[pl] + ys[pl + 1] + ys[pl + 2] + ln_b[0];
}

extern "C" void kernel_launch(void* const* d_in, const int* in_sizes, int n_in,
                              void* d_out, int out_size, void* d_ws, size_t ws_size,
                              hipStream_t stream) {
    const float* X  = (const float*)d_in[0];
    const int*   A1 = (const int*)d_in[1];
    const int*   A2 = (const int*)d_in[2];
    const int*   A3 = (const int*)d_in[3];
    const float* W11 = (const float*)d_in[5];
    const float* as11 = (const float*)d_in[6];
    const float* ad11 = (const float*)d_in[7];
    const float* b11 = (const float*)d_in[8];
    const float* W12 = (const float*)d_in[9];
    const float* as12 = (const float*)d_in[10];
    const float* ad12 = (const float*)d_in[11];
    const float* b12 = (const float*)d_in[12];
    const float* W21 = (const float*)d_in[13];
    const float* as21 = (const float*)d_in[14];
    const float* ad21 = (const float*)d_in[15];
    const float* b21 = (const float*)d_in[16];
    const float* W22 = (const float*)d_in[17];
    const float* as22 = (const float*)d_in[18];
    const float* ad22 = (const float*)d_in[19];
    const float* b22 = (const float*)d_in[20];
    const float* W31 = (const float*)d_in[21];
    const float* as31 = (const float*)d_in[22];
    const float* ad31 = (const float*)d_in[23];
    const float* b31 = (const float*)d_in[24];
    const float* W32 = (const float*)d_in[25];
    const float* as32 = (const float*)d_in[26];
    const float* ad32 = (const float*)d_in[27];
    const float* b32 = (const float*)d_in[28];
    const float* ln_w = (const float*)d_in[29];
    const float* ln_b = (const float*)d_in[30];

    const int N = in_sizes[0] / 64;
    const int E = in_sizes[1] / 2;
    const int total = 3 * N;
    const int nbA = (total + 1023) / 1024;
    const int nL1 = (N + L1_NODES - 1) / L1_NODES;
    const int nbE = (E + 383) / 384;

    // workspace layout
    float* w = (float*)d_ws;
    float* s_src1 = w; w += (size_t)N * 24;
    float* s_dst1 = w; w += (size_t)N * 24;
    float* h2     = w; w += (size_t)N * 3;
    unsigned short* h_bf = (unsigned short*)w; w += (size_t)N * 192;  // N*384 bf16
    int* iw     = (int*)w;
    int* deg    = iw; iw += (size_t)3 * N;
    int* start  = iw; iw += (size_t)3 * N;
    int* bsum   = iw; iw += 1024;
    int* deg8   = iw; iw += (size_t)24 * N;
    int* startk = iw; iw += (size_t)24 * N;
    unsigned short* epos = (unsigned short*)iw;
    unsigned short* csr  = epos + (size_t)3 * E;

    const int BLK = 256;

    hipMemsetAsync(deg8, 0, (size_t)24 * N * sizeof(int), stream);

    // ---- fused: linear1 ∥ degpos ----
    k_lin1_deg<<<nL1 + 3 * nbE, 384, 0, stream>>>(
        X, W11, W21, W31, as11, ad11, as21, ad21, as31, ad31,
        h_bf, s_src1, s_dst1,
        A1, A2, A3, deg8, epos, nL1, nbE, E, N);

    // ---- CSR scans + scatter ----
    k_scanA2<<<nbA, 256, 0, stream>>>(deg8, deg, startk, start, bsum, total, N);
    k_scanB<<<1, 256, 0, stream>>>(bsum, nbA);
    k_scanC2<<<(total + BLK - 1) / BLK, BLK, 0, stream>>>(start, bsum, startk, h2, total, N, E);
    {
        dim3 grid((E + BLK - 1) / BLK, 3);
        k_scatter2<<<grid, BLK, 0, stream>>>(A1, A2, A3, startk, epos, csr, E, N);
    }

    // ---- layer-1 aggregation (+ fused layer-2 linear) ----
    {
        dim3 grid(N, 3);
        k_agg1<<<grid, 64, 0, stream>>>(h_bf, s_src1, s_dst1, deg, start, csr,
                                        b11, b21, b31, W12, W22, W32, h2, E, N);
    }

    // ---- layer-2 aggregation + final projection ----
    {
        int nb = (total + 47) / 48;
        k_agg2f<<<nb, 384, 0, stream>>>(
            h2, deg, start, csr,
            as12, ad12, as22, ad22, as32, ad32,
            b12, b22, b32, ln_w, ln_b, (float*)d_out, E, N);
    }
}